// Round 6
// baseline (117.593 us; speedup 1.0000x reference)
//
#include <hip/hip_runtime.h>
#include <hip/hip_bf16.h>

// Fixed shape: B=4096, I=1024, H=1024
#define B_ROWS 4096
#define H_DIM  1024
#define K_DIM  2048   // I + H
#define N_DIM  4096   // 4H
#define NT32   64     // K_DIM / 32 K-tiles

typedef __attribute__((ext_vector_type(8))) short bf16x8;
typedef __attribute__((ext_vector_type(4))) float f32x4;

__device__ __forceinline__ unsigned short f2bf(float f) {
  union { float f; unsigned int u; } v; v.f = f;
  unsigned int u = v.u;
  return (unsigned short)((u + 0x7fffu + ((u >> 16) & 1u)) >> 16);
}
__device__ __forceinline__ float bf2f(unsigned short u) {
  union { unsigned int u; float f; } v; v.u = ((unsigned int)u) << 16;
  return v.f;
}

__device__ __forceinline__ void gload_lds16(const void* g, void* l) {
  __builtin_amdgcn_global_load_lds(
      (const __attribute__((address_space(1))) void*)g,
      (__attribute__((address_space(3))) void*)l, 16, 0, 0);
}

// -------- merged pack kernel: fp32 -> bf16 for A=concat(x,h) and W ---------
__global__ __launch_bounds__(256) void pack_kernel(
    const float* __restrict__ x, const float* __restrict__ h,
    const float* __restrict__ W, unsigned short* __restrict__ Abf,
    unsigned short* __restrict__ Wbf) {
  int bid = blockIdx.x;
  if (bid < 8192) {
    int t = bid * 256 + threadIdx.x;
    int e = t * 4;
    int row = e >> 11;
    int col = e & 2047;
    const float* src = (col < 1024) ? (x + (size_t)row * 1024 + col)
                                    : (h + (size_t)row * 1024 + (col - 1024));
    float4 v = *(const float4*)src;
    ushort4 o;
    o.x = f2bf(v.x); o.y = f2bf(v.y); o.z = f2bf(v.z); o.w = f2bf(v.w);
    *(ushort4*)(Abf + e) = o;
  } else {
    int t = (bid - 8192) * 256 + threadIdx.x;
    int e = t * 4;
    float4 v = *(const float4*)(W + e);
    ushort4 o;
    o.x = f2bf(v.x); o.y = f2bf(v.y); o.z = f2bf(v.z); o.w = f2bf(v.w);
    *(ushort4*)(Wbf + e) = o;
  }
}

// -------- GEMM: 256x128 tile, BK=32, 3-LDS-buffer, 2 blocks/CU -------------
// gates(bf16) = A(4096x2048 bf16) * W^T(4096x2048 bf16) + bias(fp32)
// 512 blocks (2/CU -> two independent barrier groups overlap each other's
// sync/LDS stalls). 4 waves = 2(M) x 2(N); wave-tile 128x64. LDS = 3 x 24KB
// buffers (A 16KB + B 8KB each; 16x32-bf16 subtiles of 1KB, st_16x32 swizzle
// via pre-swizzled global source + swizzled ds_read).
// Per K-tile t: stage(t+2 -> buf[(t+2)%3], 6 gloads) -> vmcnt(6) -> barrier
// -> 12 ds_read frags(t+1) from buf[(t+1)%3] -> lgkmcnt(12) -> 32 MFMA on
// frags(t) (regs, P/Q double-buffered). Staged buffer was last read 2
// barriers ago -> race-free under 1-barrier wave skew.

#define UNR _Pragma("unroll")

#define PSTG(kt, BS)                                                         \
  {                                                                          \
    const unsigned short* pA = gAw + ((size_t)(kt) << 5);                    \
    const unsigned short* pB = gBw + ((size_t)(kt) << 5);                    \
    UNR for (int i = 0; i < 4; ++i)                                          \
      gload_lds16(pA + (size_t)i * 16 * K_DIM, (BS) + (4 * w + i) * 1024);   \
    UNR for (int i = 0; i < 2; ++i)                                          \
      gload_lds16(pB + (size_t)i * 16 * K_DIM,                               \
                  (BS) + 16384 + (2 * w + i) * 1024);                        \
  }

#define TILE(tt, BS, BR, FRa, FRb, FWa, FWb)                                 \
  {                                                                          \
    const int kt2 = ((tt) + 2) & (NT32 - 1);                                 \
    PSTG(kt2, BS);                                                           \
    asm volatile("s_waitcnt vmcnt(6)" ::: "memory");                         \
    __builtin_amdgcn_s_barrier();                                            \
    UNR for (int mi = 0; mi < 8; ++mi)                                       \
      FWa[mi] = *(const bf16x8*)((BR) + (wm * 8 + mi) * 1024 + lofs);        \
    UNR for (int ni = 0; ni < 4; ++ni)                                       \
      FWb[ni] = *(const bf16x8*)((BR) + 16384 + (wn * 4 + ni) * 1024 + lofs);\
    asm volatile("s_waitcnt lgkmcnt(12)" ::: "memory");                      \
    __builtin_amdgcn_sched_barrier(0);                                       \
    __builtin_amdgcn_s_setprio(1);                                           \
    UNR for (int mi = 0; mi < 8; ++mi)                                       \
      UNR for (int ni = 0; ni < 4; ++ni)                                     \
        acc[mi][ni] = __builtin_amdgcn_mfma_f32_16x16x32_bf16(               \
            FRa[mi], FRb[ni], acc[mi][ni], 0, 0, 0);                         \
    __builtin_amdgcn_s_setprio(0);                                           \
  }

__global__ __launch_bounds__(256, 2) void gemm_kernel(
    const unsigned short* __restrict__ A, const unsigned short* __restrict__ W,
    const float* __restrict__ bias, unsigned short* __restrict__ C) {
  __shared__ __align__(16) char lds[73728];   // 3 x 24KB buffers

  const int tid = threadIdx.x;
  const int w = tid >> 6, l = tid & 63;
  const int wm = w >> 1, wn = w & 1;            // 2 x 2 wave grid

  // XCD-aware swizzle: 512 blocks on 16(M) x 32(N) grid; 8x8 rect per XCD.
  const int bid = blockIdx.x;
  const int xcd = bid & 7, li = bid >> 3;
  const int by = (xcd & 1) * 8 + (li >> 3);
  const int bx = ((xcd >> 1) << 3) + (li & 7);
  const int bm = by * 256, bn = bx * 128;

  // swizzled ds_read lane offset within a 1KB subtile (16 rows x 32 bf16)
  const int lofs = (((l & 15) * 64) + ((l >> 4) * 16)) ^ ((l & 8) << 2);
  // inverse-swizzle lane mapping for linear global_load_lds staging
  const int lane_r = (l >> 2) & 15;
  const int lane_c = ((l & 3) * 8) ^ (((l >> 5) & 1) * 16);

  // wave w stages A rows 64w..64w+63 (4 subtiles) and B rows 32w..32w+31 (2)
  const unsigned short* gAw = A + (size_t)(bm + 64 * w + lane_r) * K_DIM + lane_c;
  const unsigned short* gBw = W + (size_t)(bn + 32 * w + lane_r) * K_DIM + lane_c;

  char* const LB0 = lds;
  char* const LB1 = lds + 24576;
  char* const LB2 = lds + 49152;

  f32x4 acc[8][4];
#pragma unroll
  for (int i = 0; i < 8; ++i)
#pragma unroll
    for (int j = 0; j < 4; ++j) acc[i][j] = (f32x4)0.0f;

  // ---- prologue: stage tiles 0,1 into buf 0,1; read frags(0) -> P ----
  PSTG(0, LB0);
  PSTG(1, LB1);
  asm volatile("s_waitcnt vmcnt(6)" ::: "memory");   // tile0 landed
  __builtin_amdgcn_s_barrier();

  bf16x8 aP[8], bP[4], aQ[8], bQ[4];
#pragma unroll
  for (int mi = 0; mi < 8; ++mi)
    aP[mi] = *(const bf16x8*)(LB0 + (wm * 8 + mi) * 1024 + lofs);
#pragma unroll
  for (int ni = 0; ni < 4; ++ni)
    bP[ni] = *(const bf16x8*)(LB0 + 16384 + (wn * 4 + ni) * 1024 + lofs);

  for (int i = 0; i < 10; ++i) {
    const int t = i * 6;
    TILE(t + 0, LB2, LB1, aP, bP, aQ, bQ);
    TILE(t + 1, LB0, LB2, aQ, bQ, aP, bP);
    TILE(t + 2, LB1, LB0, aP, bP, aQ, bQ);
    TILE(t + 3, LB2, LB1, aQ, bQ, aP, bP);
    TILE(t + 4, LB0, LB2, aP, bP, aQ, bQ);
    TILE(t + 5, LB1, LB0, aQ, bQ, aP, bP);
  }
  TILE(60, LB2, LB1, aP, bP, aQ, bQ);
  TILE(61, LB0, LB2, aQ, bQ, aP, bP);
  TILE(62, LB1, LB0, aP, bP, aQ, bQ);
  TILE(63, LB2, LB1, aQ, bQ, aP, bP);

  // ---- epilogue: +bias (fp32), convert to bf16, store ----
  const int lm = l & 15, lq = l >> 4;
  float bv[4];
#pragma unroll
  for (int ni = 0; ni < 4; ++ni) bv[ni] = bias[bn + wn * 64 + ni * 16 + lm];
  unsigned short* Cb = C + (size_t)(bm + wm * 128) * N_DIM + bn + wn * 64;
#pragma unroll
  for (int mi = 0; mi < 8; ++mi)
#pragma unroll
    for (int j = 0; j < 4; ++j) {
      const size_t rofs = (size_t)(mi * 16 + lq * 4 + j) * N_DIM;
#pragma unroll
      for (int ni = 0; ni < 4; ++ni)
        Cb[rofs + ni * 16 + lm] = f2bf(acc[mi][ni][j] + bv[ni]);
    }
}

// -------- fused LN + activations + cell update -----------------------------
__device__ __forceinline__ float2 blk_sum2(float s, float q, float* red,
                                           int wid, int lane) {
#pragma unroll
  for (int o = 32; o >= 1; o >>= 1) {
    s += __shfl_xor(s, o, 64);
    q += __shfl_xor(q, o, 64);
  }
  __syncthreads();
  if (lane == 0) { red[wid * 2] = s; red[wid * 2 + 1] = q; }
  __syncthreads();
  s = red[0] + red[2] + red[4] + red[6];
  q = red[1] + red[3] + red[5] + red[7];
  return make_float2(s, q);
}

__device__ __forceinline__ float sigmoidf_(float x) {
  return 1.0f / (1.0f + __expf(-x));
}
__device__ __forceinline__ float tanhf_(float x) {
  return 1.0f - 2.0f / (__expf(2.0f * x) + 1.0f);
}

__global__ __launch_bounds__(256) void ln_lstm_kernel(
    const unsigned short* __restrict__ gates, const float* __restrict__ cprev,
    const float* __restrict__ g_i, const float* __restrict__ b_i,
    const float* __restrict__ g_f, const float* __restrict__ b_f,
    const float* __restrict__ g_g, const float* __restrict__ b_g,
    const float* __restrict__ g_o, const float* __restrict__ b_o,
    const float* __restrict__ g_c, const float* __restrict__ b_c,
    float* __restrict__ out) {
  const int b = blockIdx.x;
  const int t = threadIdx.x;
  const int wid = t >> 6, lane = t & 63;
  __shared__ float red[8];

  const unsigned short* grow = gates + (size_t)b * N_DIM;
  const int c0 = t * 4;

  float v[4][4];
#pragma unroll
  for (int g = 0; g < 4; g++) {
    ushort4 raw = *(const ushort4*)(grow + g * 1024 + c0);
    v[g][0] = bf2f(raw.x); v[g][1] = bf2f(raw.y);
    v[g][2] = bf2f(raw.z); v[g][3] = bf2f(raw.w);
  }

  const float4 gamma[4] = {*(const float4*)(g_i + c0), *(const float4*)(g_f + c0),
                           *(const float4*)(g_g + c0), *(const float4*)(g_o + c0)};
  const float4 beta[4]  = {*(const float4*)(b_i + c0), *(const float4*)(b_f + c0),
                           *(const float4*)(b_g + c0), *(const float4*)(b_o + c0)};

  float a[4][4];
#pragma unroll
  for (int g = 0; g < 4; g++) {
    float s = v[g][0] + v[g][1] + v[g][2] + v[g][3];
    float q = v[g][0]*v[g][0] + v[g][1]*v[g][1] + v[g][2]*v[g][2] + v[g][3]*v[g][3];
    float2 r = blk_sum2(s, q, red, wid, lane);
    float mu = r.x * (1.0f / 1024.0f);
    float var = r.y * (1.0f / 1024.0f) - mu * mu;
    float inv = rsqrtf(var + 1e-5f);
    const float* gm = (const float*)&gamma[g];
    const float* bt = (const float*)&beta[g];
#pragma unroll
    for (int j = 0; j < 4; j++) {
      float n = (v[g][j] - mu) * inv * gm[j] + bt[j];
      a[g][j] = (g == 2) ? tanhf_(n) : sigmoidf_(n);
    }
  }

  float4 cp = *(const float4*)(cprev + (size_t)b * 1024 + c0);
  const float* cpe = (const float*)&cp;
  float cn[4];
#pragma unroll
  for (int j = 0; j < 4; j++)
    cn[j] = a[1][j] * cpe[j] + a[0][j] * a[2][j];

  {
    float s = cn[0] + cn[1] + cn[2] + cn[3];
    float q = cn[0]*cn[0] + cn[1]*cn[1] + cn[2]*cn[2] + cn[3]*cn[3];
    float2 r = blk_sum2(s, q, red, wid, lane);
    float mu = r.x * (1.0f / 1024.0f);
    float var = r.y * (1.0f / 1024.0f) - mu * mu;
    float inv = rsqrtf(var + 1e-5f);
    float4 gm = *(const float4*)(g_c + c0);
    float4 bt = *(const float4*)(b_c + c0);
    const float* gme = (const float*)&gm;
    const float* bte = (const float*)&bt;
    float hn[4];
#pragma unroll
    for (int j = 0; j < 4; j++) {
      float n = (cn[j] - mu) * inv * gme[j] + bte[j];
      hn[j] = a[3][j] * tanhf_(n);
    }
    *(float4*)(out + (size_t)b * 1024 + c0) = make_float4(hn[0], hn[1], hn[2], hn[3]);
    *(float4*)(out + (size_t)B_ROWS * H_DIM + (size_t)b * 1024 + c0) =
        make_float4(cn[0], cn[1], cn[2], cn[3]);
  }
}

// ---------------------------------------------------------------------------
extern "C" void kernel_launch(void* const* d_in, const int* in_sizes, int n_in,
                              void* d_out, int out_size, void* d_ws,
                              size_t ws_size, hipStream_t stream) {
  const float* x    = (const float*)d_in[0];
  const float* h    = (const float*)d_in[1];
  const float* c    = (const float*)d_in[2];
  const float* W    = (const float*)d_in[3];
  const float* bias = (const float*)d_in[4];
  const float* ln_i_g = (const float*)d_in[5];
  const float* ln_i_b = (const float*)d_in[6];
  const float* ln_f_g = (const float*)d_in[7];
  const float* ln_f_b = (const float*)d_in[8];
  const float* ln_g_g = (const float*)d_in[9];
  const float* ln_g_b = (const float*)d_in[10];
  const float* ln_o_g = (const float*)d_in[11];
  const float* ln_o_b = (const float*)d_in[12];
  const float* ln_c_g = (const float*)d_in[13];
  const float* ln_c_b = (const float*)d_in[14];

  // workspace: A_bf16 (16MB) | W_bf16 (16MB) | gates bf16 (32MB)
  unsigned short* Abf = (unsigned short*)d_ws;
  unsigned short* Wbf = Abf + (size_t)B_ROWS * K_DIM;
  unsigned short* gates = Wbf + (size_t)N_DIM * K_DIM;

  pack_kernel<<<16384, 256, 0, stream>>>(x, h, W, Abf, Wbf);

  dim3 ggrid(512);
  gemm_kernel<<<ggrid, 256, 0, stream>>>(Abf, Wbf, bias, gates);

  ln_lstm_kernel<<<B_ROWS, 256, 0, stream>>>(
      gates, c, ln_i_g, ln_i_b, ln_f_g, ln_f_b, ln_g_g, ln_g_b,
      ln_o_g, ln_o_b, ln_c_g, ln_c_b, (float*)d_out);
}

// Round 7
// 111.006 us; speedup vs baseline: 1.0593x; 1.0593x over previous
//
#include <hip/hip_runtime.h>
#include <hip/hip_bf16.h>

// Fixed shape: B=4096, I=1024, H=1024
#define B_ROWS 4096
#define H_DIM  1024
#define K_DIM  2048   // I + H
#define N_DIM  4096   // 4H
#define NT32   64     // K_DIM / 32 K-tiles

typedef __attribute__((ext_vector_type(8))) short bf16x8;
typedef __attribute__((ext_vector_type(16))) float f32x16;

__device__ __forceinline__ unsigned short f2bf(float f) {
  union { float f; unsigned int u; } v; v.f = f;
  unsigned int u = v.u;
  return (unsigned short)((u + 0x7fffu + ((u >> 16) & 1u)) >> 16);
}
__device__ __forceinline__ float bf2f(unsigned short u) {
  union { unsigned int u; float f; } v; v.u = ((unsigned int)u) << 16;
  return v.f;
}

__device__ __forceinline__ void gload_lds16(const void* g, void* l) {
  __builtin_amdgcn_global_load_lds(
      (const __attribute__((address_space(1))) void*)g,
      (__attribute__((address_space(3))) void*)l, 16, 0, 0);
}

// -------- merged pack kernel: fp32 -> bf16 for A=concat(x,h) and W ---------
__global__ __launch_bounds__(256) void pack_kernel(
    const float* __restrict__ x, const float* __restrict__ h,
    const float* __restrict__ W, unsigned short* __restrict__ Abf,
    unsigned short* __restrict__ Wbf) {
  int bid = blockIdx.x;
  if (bid < 8192) {
    int t = bid * 256 + threadIdx.x;
    int e = t * 4;
    int row = e >> 11;
    int col = e & 2047;
    const float* src = (col < 1024) ? (x + (size_t)row * 1024 + col)
                                    : (h + (size_t)row * 1024 + (col - 1024));
    float4 v = *(const float4*)src;
    ushort4 o;
    o.x = f2bf(v.x); o.y = f2bf(v.y); o.z = f2bf(v.z); o.w = f2bf(v.w);
    *(ushort4*)(Abf + e) = o;
  } else {
    int t = (bid - 8192) * 256 + threadIdx.x;
    int e = t * 4;
    float4 v = *(const float4*)(W + e);
    ushort4 o;
    o.x = f2bf(v.x); o.y = f2bf(v.y); o.z = f2bf(v.z); o.w = f2bf(v.w);
    *(ushort4*)(Wbf + e) = o;
  }
}

// -------- GEMM: 256x256, BK=32, 4-LDS-buffer, 1 barrier/K-tile, MFMA 32x32 -
// gates(bf16) = A(4096x2048 bf16) * W^T(4096x2048 bf16) + bias(fp32)
// 8 waves = 2(M) x 4(N); wave-tile 128x64; mfma_f32_32x32x16_bf16.
// LDS = 4 x 32KB buffers (A 16KB + B 16KB; 16x32-bf16 subtiles of 1KB).
// Stored layout within subtile s (parity p=s&1): byte(r,k)=(r*64+2k)
//   ^ ((r&8)<<2) ^ (p<<4) — conflict-free for both 16-row staging and
//   32-row fragment reads; implemented by pre-swizzling the global source
//   (linear gload dest) and XORing the ds_read offset.
// Per K-tile t: stage(t+3) -> vmcnt(8) -> barrier -> 12 ds_read frags(t+1)
// -> lgkmcnt(12) -> 16 MFMA(32x32) on frags(t). Frag regs P/Q double-buffered.

#define UNR _Pragma("unroll")

#define PSTG(kt, BUFOFS)                                                     \
  {                                                                          \
    const size_t ko = (size_t)(kt) << 5;                                     \
    char* const Ld = lds + (BUFOFS);                                         \
    gload_lds16(gAw0 + ko, Ld + dstOfs);                                     \
    gload_lds16(gAw1 + ko, Ld + dstOfs + 1024);                              \
    gload_lds16(gBw0 + ko, Ld + 16384 + dstOfs);                             \
    gload_lds16(gBw1 + ko, Ld + 16384 + dstOfs + 1024);                      \
  }

#define TILE1(tt, BUF, FRa, FRb, FWa, FWb)                                   \
  {                                                                          \
    const int kt3 = ((tt) + 3) & (NT32 - 1);                                 \
    PSTG(kt3, (((BUF) + 3) & 3) * 32768);                                    \
    asm volatile("s_waitcnt vmcnt(8)" ::: "memory");                         \
    __builtin_amdgcn_s_barrier();                                            \
    const char* const Ln = lds + (((BUF) + 1) & 3) * 32768;                  \
    UNR for (int R = 0; R < 4; ++R) {                                        \
      FWa[R][0] = *(const bf16x8*)(Ln + (wm * 8 + 2 * R) * 1024 + lofs0);    \
      FWa[R][1] = *(const bf16x8*)(Ln + (wm * 8 + 2 * R) * 1024 + lofs1);    \
    }                                                                        \
    UNR for (int ni = 0; ni < 2; ++ni) {                                     \
      FWb[ni][0] = *(const bf16x8*)(Ln + 16384 +                             \
                                    (wn * 4 + 2 * ni) * 1024 + lofs0);       \
      FWb[ni][1] = *(const bf16x8*)(Ln + 16384 +                             \
                                    (wn * 4 + 2 * ni) * 1024 + lofs1);       \
    }                                                                        \
    asm volatile("s_waitcnt lgkmcnt(12)" ::: "memory");                      \
    __builtin_amdgcn_sched_barrier(0);                                       \
    __builtin_amdgcn_s_setprio(1);                                           \
    UNR for (int R = 0; R < 4; ++R)                                          \
      UNR for (int ni = 0; ni < 2; ++ni)                                     \
        UNR for (int h = 0; h < 2; ++h)                                      \
          acc[R][ni] = __builtin_amdgcn_mfma_f32_32x32x16_bf16(              \
              FRa[R][h], FRb[ni][h], acc[R][ni], 0, 0, 0);                   \
    __builtin_amdgcn_s_setprio(0);                                           \
  }

__global__ __launch_bounds__(512, 2) void gemm_kernel(
    const unsigned short* __restrict__ A, const unsigned short* __restrict__ W,
    const float* __restrict__ bias, unsigned short* __restrict__ C) {
  __shared__ __align__(16) char lds[131072];

  const int tid = threadIdx.x;
  const int w = tid >> 6, l = tid & 63;
  const int wm = w >> 2, wn = w & 3;            // 2 x 4 wave grid

  // XCD-aware swizzle: 256 blocks, 8 XCDs, each XCD owns a 4x8 rect.
  const int bid = blockIdx.x;
  const int xcd = bid & 7, li = bid >> 3;
  const int by = (xcd & 3) * 4 + (li >> 3);
  const int bx = ((xcd >> 2) << 3) + (li & 7);
  const int bm = by * 256, bn = bx * 256;

  // 32-row fragment read offset (subtile-pair): lane l -> row l&31,
  // k = h*16 + (l>>5)*8 (.. +7). Includes parity XOR bit.
  const int lofs0 = ((l >> 4) & 1) * 1024 + (l & 15) * 64 +
                    ((((l >> 5) * 16) ^ ((l & 8) << 2)) ^ (((l >> 4) & 1) << 4));
  const int lofs1 = lofs0 ^ 32;

  // inverse-swizzle lane mapping for linear global_load_lds staging
  const int lane_r = (l >> 2) & 15;
  const int lane_c0 = ((l & 3) * 8) ^ (((l >> 5) & 1) * 16);      // parity 0
  const int lane_c1 = lane_c0 ^ 8;                                 // parity 1

  // wave w stages A rows 32w..32w+31 and B rows 32w..32w+31 (2 subtiles each)
  const int dstOfs = w * 2048;
  const unsigned short* gAw0 = A + (size_t)(bm + 32 * w + lane_r) * K_DIM + lane_c0;
  const unsigned short* gAw1 = A + (size_t)(bm + 32 * w + 16 + lane_r) * K_DIM + lane_c1;
  const unsigned short* gBw0 = W + (size_t)(bn + 32 * w + lane_r) * K_DIM + lane_c0;
  const unsigned short* gBw1 = W + (size_t)(bn + 32 * w + 16 + lane_r) * K_DIM + lane_c1;

  f32x16 acc[4][2];
#pragma unroll
  for (int i = 0; i < 4; ++i)
#pragma unroll
    for (int j = 0; j < 2; ++j) acc[i][j] = (f32x16)0.0f;

  // ---- prologue: stage tiles 0,1,2 into buf 0,1,2 ----
  PSTG(0, 0);
  PSTG(1, 32768);
  PSTG(2, 65536);
  asm volatile("s_waitcnt vmcnt(8)" ::: "memory");   // tile0 landed
  __builtin_amdgcn_s_barrier();

  bf16x8 aP[4][2], bP[2][2], aQ[4][2], bQ[2][2];
#pragma unroll
  for (int R = 0; R < 4; ++R) {
    aP[R][0] = *(const bf16x8*)(lds + (wm * 8 + 2 * R) * 1024 + lofs0);
    aP[R][1] = *(const bf16x8*)(lds + (wm * 8 + 2 * R) * 1024 + lofs1);
  }
#pragma unroll
  for (int ni = 0; ni < 2; ++ni) {
    bP[ni][0] = *(const bf16x8*)(lds + 16384 + (wn * 4 + 2 * ni) * 1024 + lofs0);
    bP[ni][1] = *(const bf16x8*)(lds + 16384 + (wn * 4 + 2 * ni) * 1024 + lofs1);
  }

  for (int t = 0; t < NT32; t += 4) {
    TILE1(t + 0, 0, aP, bP, aQ, bQ);
    TILE1(t + 1, 1, aQ, bQ, aP, bP);
    TILE1(t + 2, 2, aP, bP, aQ, bQ);
    TILE1(t + 3, 3, aQ, bQ, aP, bP);
  }

  // ---- epilogue: +bias (fp32), bf16 convert, store ----
  // C/D 32x32 layout: col = lane&31, row = (reg&3) + 8*(reg>>2) + 4*(lane>>5)
  const int cl = l & 31, hi = l >> 5;
  float bv[2];
#pragma unroll
  for (int ni = 0; ni < 2; ++ni) bv[ni] = bias[bn + wn * 64 + ni * 32 + cl];
  unsigned short* Cb = C + (size_t)(bm + wm * 128) * N_DIM + bn + wn * 64;
#pragma unroll
  for (int R = 0; R < 4; ++R)
#pragma unroll
    for (int ni = 0; ni < 2; ++ni)
#pragma unroll
      for (int r = 0; r < 16; ++r) {
        const int row = R * 32 + (r & 3) + 8 * (r >> 2) + 4 * hi;
        Cb[(size_t)row * N_DIM + ni * 32 + cl] = f2bf(acc[R][ni][r] + bv[ni]);
      }
}

// -------- fused LN + activations + cell update -----------------------------
__device__ __forceinline__ float sigmoidf_(float x) {
  return 1.0f / (1.0f + __expf(-x));
}
__device__ __forceinline__ float tanhf_(float x) {
  return 1.0f - 2.0f / (__expf(2.0f * x) + 1.0f);
}

__global__ __launch_bounds__(256) void ln_lstm_kernel(
    const unsigned short* __restrict__ gates, const float* __restrict__ cprev,
    const float* __restrict__ g_i, const float* __restrict__ b_i,
    const float* __restrict__ g_f, const float* __restrict__ b_f,
    const float* __restrict__ g_g, const float* __restrict__ b_g,
    const float* __restrict__ g_o, const float* __restrict__ b_o,
    const float* __restrict__ g_c, const float* __restrict__ b_c,
    float* __restrict__ out) {
  const int b = blockIdx.x;
  const int t = threadIdx.x;
  const int wid = t >> 6, lane = t & 63;
  __shared__ float red[32];

  const unsigned short* grow = gates + (size_t)b * N_DIM;
  const int c0 = t * 4;

  float v[4][4];
#pragma unroll
  for (int g = 0; g < 4; g++) {
    ushort4 raw = *(const ushort4*)(grow + g * 1024 + c0);
    v[g][0] = bf2f(raw.x); v[g][1] = bf2f(raw.y);
    v[g][2] = bf2f(raw.z); v[g][3] = bf2f(raw.w);
  }

  const float4 gamma[4] = {*(const float4*)(g_i + c0), *(const float4*)(g_f + c0),
                           *(const float4*)(g_g + c0), *(const float4*)(g_o + c0)};
  const float4 beta[4]  = {*(const float4*)(b_i + c0), *(const float4*)(b_f + c0),
                           *(const float4*)(b_g + c0), *(const float4*)(b_o + c0)};

  // batched reduce: 4 sums + 4 sumsqs in one pass (3 barriers total in kernel)
  float s[8];
#pragma unroll
  for (int g = 0; g < 4; g++) {
    s[g]     = v[g][0] + v[g][1] + v[g][2] + v[g][3];
    s[4 + g] = v[g][0]*v[g][0] + v[g][1]*v[g][1] + v[g][2]*v[g][2] + v[g][3]*v[g][3];
  }
#pragma unroll
  for (int o = 32; o >= 1; o >>= 1)
#pragma unroll
    for (int i = 0; i < 8; i++) s[i] += __shfl_xor(s[i], o, 64);
  if (lane == 0) {
#pragma unroll
    for (int i = 0; i < 8; i++) red[wid * 8 + i] = s[i];
  }
  __syncthreads();
#pragma unroll
  for (int i = 0; i < 8; i++) s[i] = red[i] + red[8 + i] + red[16 + i] + red[24 + i];

  float a[4][4];
#pragma unroll
  for (int g = 0; g < 4; g++) {
    float mu = s[g] * (1.0f / 1024.0f);
    float var = s[4 + g] * (1.0f / 1024.0f) - mu * mu;
    float inv = rsqrtf(var + 1e-5f);
    const float* gm = (const float*)&gamma[g];
    const float* bt = (const float*)&beta[g];
#pragma unroll
    for (int j = 0; j < 4; j++) {
      float n = (v[g][j] - mu) * inv * gm[j] + bt[j];
      a[g][j] = (g == 2) ? tanhf_(n) : sigmoidf_(n);
    }
  }

  float4 cp = *(const float4*)(cprev + (size_t)b * 1024 + c0);
  const float* cpe = (const float*)&cp;
  float cn[4];
#pragma unroll
  for (int j = 0; j < 4; j++)
    cn[j] = a[1][j] * cpe[j] + a[0][j] * a[2][j];

  {
    float u0 = cn[0] + cn[1] + cn[2] + cn[3];
    float u1 = cn[0]*cn[0] + cn[1]*cn[1] + cn[2]*cn[2] + cn[3]*cn[3];
#pragma unroll
    for (int o = 32; o >= 1; o >>= 1) {
      u0 += __shfl_xor(u0, o, 64);
      u1 += __shfl_xor(u1, o, 64);
    }
    __syncthreads();   // all reads of red (round 1) done before overwrite
    if (lane == 0) { red[wid * 2] = u0; red[wid * 2 + 1] = u1; }
    __syncthreads();
    u0 = red[0] + red[2] + red[4] + red[6];
    u1 = red[1] + red[3] + red[5] + red[7];
    float mu = u0 * (1.0f / 1024.0f);
    float var = u1 * (1.0f / 1024.0f) - mu * mu;
    float inv = rsqrtf(var + 1e-5f);
    float4 gm = *(const float4*)(g_c + c0);
    float4 bt = *(const float4*)(b_c + c0);
    const float* gme = (const float*)&gm;
    const float* bte = (const float*)&bt;
    float hn[4];
#pragma unroll
    for (int j = 0; j < 4; j++) {
      float n = (cn[j] - mu) * inv * gme[j] + bte[j];
      hn[j] = a[3][j] * tanhf_(n);
    }
    *(float4*)(out + (size_t)b * 1024 + c0) = make_float4(hn[0], hn[1], hn[2], hn[3]);
    *(float4*)(out + (size_t)B_ROWS * H_DIM + (size_t)b * 1024 + c0) =
        make_float4(cn[0], cn[1], cn[2], cn[3]);
  }
}

// ---------------------------------------------------------------------------
extern "C" void kernel_launch(void* const* d_in, const int* in_sizes, int n_in,
                              void* d_out, int out_size, void* d_ws,
                              size_t ws_size, hipStream_t stream) {
  const float* x    = (const float*)d_in[0];
  const float* h    = (const float*)d_in[1];
  const float* c    = (const float*)d_in[2];
  const float* W    = (const float*)d_in[3];
  const float* bias = (const float*)d_in[4];
  const float* ln_i_g = (const float*)d_in[5];
  const float* ln_i_b = (const float*)d_in[6];
  const float* ln_f_g = (const float*)d_in[7];
  const float* ln_f_b = (const float*)d_in[8];
  const float* ln_g_g = (const float*)d_in[9];
  const float* ln_g_b = (const float*)d_in[10];
  const float* ln_o_g = (const float*)d_in[11];
  const float* ln_o_b = (const float*)d_in[12];
  const float* ln_c_g = (const float*)d_in[13];
  const float* ln_c_b = (const float*)d_in[14];

  // workspace: A_bf16 (16MB) | W_bf16 (16MB) | gates bf16 (32MB)
  unsigned short* Abf = (unsigned short*)d_ws;
  unsigned short* Wbf = Abf + (size_t)B_ROWS * K_DIM;
  unsigned short* gates = Wbf + (size_t)N_DIM * K_DIM;

  pack_kernel<<<16384, 256, 0, stream>>>(x, h, W, Abf, Wbf);

  dim3 ggrid(256);
  gemm_kernel<<<ggrid, 512, 0, stream>>>(Abf, Wbf, bias, gates);

  ln_lstm_kernel<<<B_ROWS, 256, 0, stream>>>(
      gates, c, ln_i_g, ln_i_b, ln_f_g, ln_f_b, ln_g_g, ln_g_b,
      ln_o_g, ln_o_b, ln_c_g, ln_c_b, (float*)d_out);
}